// Round 23
// baseline (212.013 us; speedup 1.0000x reference)
//
#include <hip/hip_runtime.h>
#include <hip/hip_bf16.h>
#include <cstddef>
#include <cstdint>

#define T_TOK 4096
#define H_DIM 2048
#define E_NUM 8
#define I_DIM 1024
#define TWO_I 2048
#define MROWS 5120      // worst-case 128-padded slot rows
#define MT2   80        // MROWS/64 M-tiles

typedef __attribute__((ext_vector_type(8))) short bf16x8;
typedef __attribute__((ext_vector_type(4))) float f32x4;
typedef __attribute__((ext_vector_type(4))) int   i32x4;

// -------- workspace layout (bytes); ws >= 134217728 proven --------
#define WS_SCALE   0               // f32[4096]
#define WS_COUNTS  16384           // int[256] padded (1 counter / 128B line)
#define WS_BUCKETS 18432           // int[8*4096] ends 149504
#define WS_SLOTTOK 149504          // int[5120]   ends 169984
#define WS_XSG     (1u<<20)        // bf16[5120*2048] ends 22020096
#define WS_ACT     22020096u       // bf16[5120*1024] ends 32505856
#define WS_W1T     32505856u       // bf16[8][2048][2048] ends 99614720
#define WS_W2T     99614720u       // bf16[8][2048][1024] ends 133169152

__device__ __forceinline__ short f2bf(float f) {
    uint32_t u = __builtin_bit_cast(uint32_t, f);
    u += 0x7fffu + ((u >> 16) & 1u);
    return (short)(u >> 16);
}

__device__ __forceinline__ void gload16(const void* g, void* l) {
    __builtin_amdgcn_global_load_lds(
        (const __attribute__((address_space(1))) void*)g,
        (__attribute__((address_space(3))) void*)l, 16, 0, 0);
}

// ---------------- LDS-exchange transpose+cvt body (r10-proven) --------------
__device__ __forceinline__ void tlds_body(
    const float* __restrict__ src, short* __restrict__ dst,
    int K, int e, int k0, int n0, float* s)
{
    const int N = TWO_I;
    const int t = threadIdx.x;

    const float* S = src + ((size_t)e * K + k0) * N + n0;
    const int kr = t >> 4, nc = (t & 15) * 4;
#pragma unroll
    for (int i = 0; i < 4; ++i) {
        float4 v = *(const float4*)(S + (size_t)(kr + i * 16) * N + nc);
        s[(kr + i * 16) * 65 + nc + 0] = v.x;
        s[(kr + i * 16) * 65 + nc + 1] = v.y;
        s[(kr + i * 16) * 65 + nc + 2] = v.z;
        s[(kr + i * 16) * 65 + nc + 3] = v.w;
    }
    __syncthreads();

    const int nr = t >> 2, kc = (t & 3) * 16;
    short tmp[16] __attribute__((aligned(16)));
#pragma unroll
    for (int j = 0; j < 16; ++j) tmp[j] = f2bf(s[(kc + j) * 65 + nr]);
    short* D = dst + ((size_t)e * N + n0 + nr) * K + k0 + kc;
    *(i32x4*)D       = *(const i32x4*)tmp;
    *(i32x4*)(D + 8) = *(const i32x4*)(tmp + 8);
}

// ---------------- router body (padded atomic counters) ----------------------
__device__ __forceinline__ void router_body(
    int blk, const float* __restrict__ x, const float* __restrict__ gw,
    float* __restrict__ scale, int* __restrict__ counts, int* __restrict__ buckets)
{
    const int wid  = threadIdx.x >> 6;
    const int lane = threadIdx.x & 63;
    const int t = blk * 4 + wid;
    if (t >= T_TOK) return;

    float4 a4[E_NUM];
#pragma unroll
    for (int e = 0; e < E_NUM; ++e) a4[e] = make_float4(0.f, 0.f, 0.f, 0.f);

    const float4* xr  = (const float4*)(x + (size_t)t * H_DIM);
    const float4* gwv = (const float4*)gw;
#pragma unroll
    for (int it = 0; it < 8; ++it) {
        const int idx = lane + it * 64;
        float4 xv = xr[idx];
#pragma unroll
        for (int e = 0; e < E_NUM; ++e) {
            float4 wv = gwv[e * 512 + idx];
            a4[e].x = fmaf(xv.x, wv.x, a4[e].x);
            a4[e].y = fmaf(xv.y, wv.y, a4[e].y);
            a4[e].z = fmaf(xv.z, wv.z, a4[e].z);
            a4[e].w = fmaf(xv.w, wv.w, a4[e].w);
        }
    }
    float acc[E_NUM];
#pragma unroll
    for (int e = 0; e < E_NUM; ++e) {
        float v = (a4[e].x + a4[e].y) + (a4[e].z + a4[e].w);
#pragma unroll
        for (int off = 32; off > 0; off >>= 1) v += __shfl_xor(v, off);
        acc[e] = v;
    }
    if (lane == 0) {
        int best = 0; float bv = acc[0];
#pragma unroll
        for (int e = 1; e < E_NUM; ++e) { if (acc[e] > bv) { bv = acc[e]; best = e; } }
        scale[t] = 1.f / (1.f + expf(-bv));
        int pos = atomicAdd(&counts[best << 5], 1);
        buckets[best * T_TOK + pos] = t;
    }
}

// ---------------- prep: router + w1t cvt (LDS transpose) --------------------
__global__ __launch_bounds__(256) void prep_kernel(
    const float* __restrict__ x, const float* __restrict__ gw,
    const float* __restrict__ gup,
    float* __restrict__ scale, int* __restrict__ counts,
    int* __restrict__ buckets, short* __restrict__ w1t)
{
    __shared__ float s[64 * 65];
    const int b = blockIdx.x;
    if (b < 1024) { router_body(b, x, gw, scale, counts, buckets); return; }

    const int idx = b - 1024;            // T1: gup [e][2048][2048], 8192 blocks
    tlds_body(gup, w1t, H_DIM, idx >> 10, (idx & 31) * 64, ((idx >> 5) & 31) * 64, s);
}

// ---------------- gather (inline padded prefix; solo) -----------------------
__global__ __launch_bounds__(256) void gather_kernel(
    const float* __restrict__ x, const float* __restrict__ scale,
    const int* __restrict__ counts, const int* __restrict__ buckets,
    short* __restrict__ xsg, int* __restrict__ slot_tok)
{
    const int r = blockIdx.x;            // slot row 0..5119
    int run = 0, eSel = 0, pos = 0;
    bool valid = false;
#pragma unroll
    for (int k = 0; k < E_NUM; ++k) {
        const int c  = counts[k << 5];
        const int cp = (c + 127) & ~127;
        if (r >= run && r < run + cp) { eSel = k; pos = r - run; valid = (pos < c); }
        run += cp;
    }
    const int tok = valid ? buckets[eSel * T_TOK + pos] : -1;
    if (threadIdx.x == 0) slot_tok[r] = tok;

    short* orow = xsg + (size_t)r * H_DIM + threadIdx.x * 8;
    if (!valid) {
        i32x4 z = {0, 0, 0, 0};
        *(i32x4*)orow = z;
        return;
    }
    const float sc = scale[tok];
    const float* xr = x + (size_t)tok * H_DIM + threadIdx.x * 8;
    float4 a = *(const float4*)xr;
    float4 c4 = *(const float4*)(xr + 4);
    short o[8] __attribute__((aligned(16)));
    o[0] = f2bf(a.x * sc);  o[1] = f2bf(a.y * sc);
    o[2] = f2bf(a.z * sc);  o[3] = f2bf(a.w * sc);
    o[4] = f2bf(c4.x * sc); o[5] = f2bf(c4.y * sc);
    o[6] = f2bf(c4.z * sc); o[7] = f2bf(c4.w * sc);
    *(i32x4*)orow = *(const i32x4*)o;
}

// ================== grouped MFMA GEMMs: M=64 tiles, 1280 blocks =============
// 3-slot counted-vmcnt pipeline + bank swizzle (r17/r22-proven). 4 waves,
// 2x2 wave split: wave (wr,wc) owns 32x64 quadrant. LDS 36KB -> 4 blocks/CU.
// Per-wave 3 gloads/iter -> vmcnt 6/3/0.

#define GEMM_PIPE(NKT)                                                         \
    STG(0, 0); STG(1, 32); STG(2, 64);                                         \
    int cb = 0;                                                                \
    for (int t = 0; t < (NKT); ++t) {                                          \
        const int rem = (NKT) - 1 - t;                                         \
        if (rem >= 2)      asm volatile("s_waitcnt vmcnt(6)" ::: "memory");    \
        else if (rem == 1) asm volatile("s_waitcnt vmcnt(3)" ::: "memory");    \
        else               asm volatile("s_waitcnt vmcnt(0)" ::: "memory");    \
        __builtin_amdgcn_s_barrier();                                          \
        CMP(cb);                                                               \
        asm volatile("s_waitcnt lgkmcnt(0)" ::: "memory");                     \
        __builtin_amdgcn_sched_barrier(0);                                     \
        __builtin_amdgcn_s_barrier();                                          \
        if (t + 3 < (NKT)) STG(cb, (t + 3) * 32);                              \
        cb = (cb == 2) ? 0 : cb + 1;                                           \
    }

// ---------------- GEMM1 + SwiGLU, fused w2t cvt -----------------------------
// blocks [0,1280): gemm (64 rows x 64 f); [1280,5376): dw -> w2t cvt
__global__ __launch_bounds__(256) void gemm1_mfma_kernel(
    const short* __restrict__ xsg, const short* __restrict__ w1t,
    const int* __restrict__ counts, short* __restrict__ act,
    const float* __restrict__ dw, short* __restrict__ w2t)
{
    __shared__ short sA[3][2048];    // 64 rows x 32 k
    __shared__ short sB[3][4096];    // 128 rows x 32 k

    const int bid = blockIdx.x;
    if (bid >= 1280) {
        const int idx = bid - 1280;      // T2: dw [e][1024][2048], 4096 blocks
        float* s = (float*)&sB[0][0];    // 16.6 KB < 24 KB (sB region)
        tlds_body(dw, w2t, I_DIM, idx >> 9, (idx & 15) * 64, ((idx >> 4) & 31) * 64, s);
        return;
    }

    const int wg  = (bid & 7) * 160 + (bid >> 3);  // bijective: 1280 % 8 == 0
    const int nt  = wg / MT2;                      // 0..15
    const int mt  = wg - nt * MT2;
    const int m0  = mt << 6;
    const int f0  = nt << 6;

    int run = 0, e = 0;
#pragma unroll
    for (int k = 0; k < E_NUM; ++k) {
        if (m0 >= run) e = k;
        run += (counts[k << 5] + 127) & ~127;
    }
    if (m0 >= run) return;

    const int tid = threadIdx.x, lane = tid & 63, w = tid >> 6;
    const int wr = w >> 1, wc = w & 1;
    const int lr = lane >> 2;
    const int cg = ((lane & 3) - (lane >> 3)) & 3;   // swizzled source chunk

    // A: 64 rows, wave w stages unit w (rows w*16..w*16+15)
    const short* srcA = xsg + (size_t)(m0 + w * 16 + lr) * H_DIM + cg * 8;
    // B: 128 rows (64 up + 64 gate), wave w stages units 2w, 2w+1
    const int rB0 = w * 32 + lr, rB1 = rB0 + 16;
    auto growf = [&](int rb) { return (rb < 64) ? (f0 + rb) : (I_DIM + f0 + (rb - 64)); };
    const short* srcB0 = w1t + ((size_t)e * TWO_I + growf(rB0)) * H_DIM + cg * 8;
    const short* srcB1 = w1t + ((size_t)e * TWO_I + growf(rB1)) * H_DIM + cg * 8;

    const int lm = lane & 15, lg = lane >> 4;
    const int ch = ((lg + (lm >> 1)) & 3) * 8;       // swizzled read chunk

    f32x4 acc[2][4];
#pragma unroll
    for (int i = 0; i < 2; ++i)
#pragma unroll
        for (int j = 0; j < 4; ++j) acc[i][j] = (f32x4){0.f, 0.f, 0.f, 0.f};

    auto STG = [&](int buf, int kb) {
        gload16(srcA + kb, &sA[buf][w * 512]);
        gload16(srcB0 + kb, &sB[buf][(2 * w) * 512]);
        gload16(srcB1 + kb, &sB[buf][(2 * w + 1) * 512]);
    };
    auto CMP = [&](int buf) {
        bf16x8 av[2], bv[4];
#pragma unroll
        for (int mf = 0; mf < 2; ++mf)
            av[mf] = *(const bf16x8*)&sA[buf][(wr * 32 + mf * 16 + lm) * 32 + ch];
#pragma unroll
        for (int j = 0; j < 4; ++j) {
            const int bf = wc * 2 + ((j < 2) ? j : (j + 2));   // 2wc,2wc+1,2wc+4,2wc+5
            bv[j] = *(const bf16x8*)&sB[buf][(bf * 16 + lm) * 32 + ch];
        }
#pragma unroll
        for (int mf = 0; mf < 2; ++mf)
#pragma unroll
            for (int j = 0; j < 4; ++j)
                acc[mf][j] = __builtin_amdgcn_mfma_f32_16x16x32_bf16(av[mf], bv[j], acc[mf][j], 0, 0, 0);
    };

    GEMM_PIPE(H_DIM / 32)   // 64 K-iters

    // epilogue: act = up * gate * sigmoid(gate); up = acc[.][j], gate = acc[.][j+2]
    const int rbase = wr * 32 + lg * 4;
#pragma unroll
    for (int mf = 0; mf < 2; ++mf) {
#pragma unroll
        for (int rr = 0; rr < 4; ++rr) {
            const int row = rbase + mf * 16 + rr;
            short* orow = act + (size_t)(m0 + row) * I_DIM + f0 + lm;
#pragma unroll
            for (int j = 0; j < 2; ++j) {
                float up = acc[mf][j][rr];
                float gt = acc[mf][j + 2][rr];
                float v  = up * gt / (1.f + expf(-gt));
                orow[(2 * wc + j) * 16] = f2bf(v);
            }
        }
    }
}

// ---------------- GEMM2 (M=64 x N=128; dense slots -> scatter out) ----------
__global__ __launch_bounds__(256) void gemm2_mfma_kernel(
    const short* __restrict__ actm, const short* __restrict__ w2t,
    const int* __restrict__ counts, const int* __restrict__ slot_tok,
    float* __restrict__ out)
{
    __shared__ short sA[3][2048];
    __shared__ short sB[3][4096];
    __shared__ int   sTok[64];

    const int bid = blockIdx.x;
    const int wg  = (bid & 7) * 160 + (bid >> 3);  // 1280 % 8 == 0
    const int nt  = wg / MT2;                      // 0..15
    const int mt  = wg - nt * MT2;
    const int m0  = mt << 6;
    const int h0  = nt << 7;                       // 128 h-cols per tile

    int run = 0, e = 0;
#pragma unroll
    for (int k = 0; k < E_NUM; ++k) {
        if (m0 >= run) e = k;
        run += (counts[k << 5] + 127) & ~127;
    }
    if (m0 >= run) return;

    const int tid = threadIdx.x, lane = tid & 63, w = tid >> 6;
    if (tid < 64) sTok[tid] = slot_tok[m0 + tid];

    const int wr = w >> 1, wc = w & 1;
    const int lr = lane >> 2;
    const int cg = ((lane & 3) - (lane >> 3)) & 3;

    const short* srcA = actm + (size_t)(m0 + w * 16 + lr) * I_DIM + cg * 8;
    const int rB0 = w * 32 + lr, rB1 = rB0 + 16;
    const short* srcB0 = w2t + ((size_t)e * H_DIM + h0 + rB0) * I_DIM + cg * 8;
    const short* srcB1 = w2t + ((size_t)e * H_DIM + h0 + rB1) * I_DIM + cg * 8;

    const int lm = lane & 15, lg = lane >> 4;
    const int ch = ((lg + (lm >> 1)) & 3) * 8;

    f32x4 acc[2][4];
#pragma unroll
    for (int i = 0; i < 2; ++i)
#pragma unroll
        for (int j = 0; j < 4; ++j) acc[i][j] = (f32x4){0.f, 0.f, 0.f, 0.f};

    auto STG = [&](int buf, int kb) {
        gload16(srcA + kb, &sA[buf][w * 512]);
        gload16(srcB0 + kb, &sB[buf][(2 * w) * 512]);
        gload16(srcB1 + kb, &sB[buf][(2 * w + 1) * 512]);
    };
    auto CMP = [&](int buf) {
        bf16x8 av[2], bv[4];
#pragma unroll
        for (int mf = 0; mf < 2; ++mf)
            av[mf] = *(const bf16x8*)&sA[buf][(wr * 32 + mf * 16 + lm) * 32 + ch];
#pragma unroll
        for (int j = 0; j < 4; ++j)
            bv[j] = *(const bf16x8*)&sB[buf][((wc * 4 + j) * 16 + lm) * 32 + ch];
#pragma unroll
        for (int mf = 0; mf < 2; ++mf)
#pragma unroll
            for (int j = 0; j < 4; ++j)
                acc[mf][j] = __builtin_amdgcn_mfma_f32_16x16x32_bf16(av[mf], bv[j], acc[mf][j], 0, 0, 0);
    };

    GEMM_PIPE(I_DIM / 32)   // 32 K-iters

    const int rbase = wr * 32 + lg * 4;
#pragma unroll
    for (int mf = 0; mf < 2; ++mf) {
#pragma unroll
        for (int rr = 0; rr < 4; ++rr) {
            const int row = rbase + mf * 16 + rr;
            const int tok = sTok[row];
            if (tok < 0) continue;
            float* orow = out + (size_t)tok * H_DIM + h0 + lm;
#pragma unroll
            for (int j = 0; j < 4; ++j) orow[(wc * 4 + j) * 16] = acc[mf][j][rr];
        }
    }
}

extern "C" void kernel_launch(void* const* d_in, const int* in_sizes, int n_in,
                              void* d_out, int out_size, void* d_ws, size_t ws_size,
                              hipStream_t stream) {
    const float* x   = (const float*)d_in[0];
    const float* gw  = (const float*)d_in[1];
    const float* gup = (const float*)d_in[2];
    const float* dw  = (const float*)d_in[3];
    float* out = (float*)d_out;

    char* ws = (char*)d_ws;
    float* scale    = (float*)(ws + WS_SCALE);
    int*   counts   = (int*)(ws + WS_COUNTS);
    int*   buckets  = (int*)(ws + WS_BUCKETS);
    int*   slot_tok = (int*)(ws + WS_SLOTTOK);
    short* xsg      = (short*)(ws + WS_XSG);
    short* act      = (short*)(ws + WS_ACT);
    short* w1t      = (short*)(ws + WS_W1T);
    short* w2t      = (short*)(ws + WS_W2T);

    hipMemsetAsync(counts, 0, 256 * sizeof(int), stream);

    // router + w1t cvt (LDS transpose)
    prep_kernel<<<1024 + 8192, 256, 0, stream>>>(
        x, gw, gup, scale, counts, buckets, w1t);

    // gather (solo, inline prefix)
    gather_kernel<<<MROWS, 256, 0, stream>>>(
        x, scale, counts, buckets, xsg, slot_tok);

    // gemm1 (1280 M=64 blocks) + w2t cvt (4096 blocks)
    gemm1_mfma_kernel<<<1280 + 4096, 256, 0, stream>>>(xsg, w1t, counts, act, dw, w2t);

    // gemm2 (1280 M=64 blocks)
    gemm2_mfma_kernel<<<1280, 256, 0, stream>>>(act, w2t, counts, slot_tok, out);
}

// Round 24
// 173.567 us; speedup vs baseline: 1.2215x; 1.2215x over previous
//
#include <hip/hip_runtime.h>
#include <hip/hip_bf16.h>
#include <cstddef>
#include <cstdint>

#define T_TOK 4096
#define H_DIM 2048
#define E_NUM 8
#define I_DIM 1024
#define TWO_I 2048
#define MROWS 5120      // worst-case 128-padded slot rows
#define MT    40        // MROWS/128 M-tiles

typedef __attribute__((ext_vector_type(8))) short bf16x8;
typedef __attribute__((ext_vector_type(4))) float f32x4;
typedef __attribute__((ext_vector_type(4))) int   i32x4;

// -------- workspace layout (bytes); ws >= 134217728 proven --------
#define WS_SCALE   0               // f32[4096]
#define WS_COUNTS  16384           // int[256] padded (1 counter / 128B line)
#define WS_BUCKETS 18432           // int[8*4096] ends 149504
#define WS_SLOTTOK 149504          // int[5120]   ends 169984
#define WS_XSG     (1u<<20)        // bf16[5120*2048] ends 22020096
#define WS_ACT     22020096u       // bf16[5120*1024] ends 32505856
#define WS_W1T     32505856u       // bf16[8][2048][2048] ends 99614720
#define WS_W2T     99614720u       // bf16[8][2048][1024] ends 133169152

__device__ __forceinline__ short f2bf(float f) {
    uint32_t u = __builtin_bit_cast(uint32_t, f);
    u += 0x7fffu + ((u >> 16) & 1u);
    return (short)(u >> 16);
}

__device__ __forceinline__ void gload16(const void* g, void* l) {
    __builtin_amdgcn_global_load_lds(
        (const __attribute__((address_space(1))) void*)g,
        (__attribute__((address_space(3))) void*)l, 16, 0, 0);
}

// ---------------- LDS-exchange transpose+cvt body (r10-proven) --------------
__device__ __forceinline__ void tlds_body(
    const float* __restrict__ src, short* __restrict__ dst,
    int K, int e, int k0, int n0, float* s)
{
    const int N = TWO_I;
    const int t = threadIdx.x;

    const float* S = src + ((size_t)e * K + k0) * N + n0;
    const int kr = t >> 4, nc = (t & 15) * 4;
#pragma unroll
    for (int i = 0; i < 4; ++i) {
        float4 v = *(const float4*)(S + (size_t)(kr + i * 16) * N + nc);
        s[(kr + i * 16) * 65 + nc + 0] = v.x;
        s[(kr + i * 16) * 65 + nc + 1] = v.y;
        s[(kr + i * 16) * 65 + nc + 2] = v.z;
        s[(kr + i * 16) * 65 + nc + 3] = v.w;
    }
    __syncthreads();

    const int nr = t >> 2, kc = (t & 3) * 16;
    short tmp[16] __attribute__((aligned(16)));
#pragma unroll
    for (int j = 0; j < 16; ++j) tmp[j] = f2bf(s[(kc + j) * 65 + nr]);
    short* D = dst + ((size_t)e * N + n0 + nr) * K + k0 + kc;
    *(i32x4*)D       = *(const i32x4*)tmp;
    *(i32x4*)(D + 8) = *(const i32x4*)(tmp + 8);
}

// ---------------- router body (padded atomic counters) ----------------------
__device__ __forceinline__ void router_body(
    int blk, const float* __restrict__ x, const float* __restrict__ gw,
    float* __restrict__ scale, int* __restrict__ counts, int* __restrict__ buckets)
{
    const int wid  = threadIdx.x >> 6;
    const int lane = threadIdx.x & 63;
    const int t = blk * 4 + wid;
    if (t >= T_TOK) return;

    float4 a4[E_NUM];
#pragma unroll
    for (int e = 0; e < E_NUM; ++e) a4[e] = make_float4(0.f, 0.f, 0.f, 0.f);

    const float4* xr  = (const float4*)(x + (size_t)t * H_DIM);
    const float4* gwv = (const float4*)gw;
#pragma unroll
    for (int it = 0; it < 8; ++it) {
        const int idx = lane + it * 64;
        float4 xv = xr[idx];
#pragma unroll
        for (int e = 0; e < E_NUM; ++e) {
            float4 wv = gwv[e * 512 + idx];
            a4[e].x = fmaf(xv.x, wv.x, a4[e].x);
            a4[e].y = fmaf(xv.y, wv.y, a4[e].y);
            a4[e].z = fmaf(xv.z, wv.z, a4[e].z);
            a4[e].w = fmaf(xv.w, wv.w, a4[e].w);
        }
    }
    float acc[E_NUM];
#pragma unroll
    for (int e = 0; e < E_NUM; ++e) {
        float v = (a4[e].x + a4[e].y) + (a4[e].z + a4[e].w);
#pragma unroll
        for (int off = 32; off > 0; off >>= 1) v += __shfl_xor(v, off);
        acc[e] = v;
    }
    if (lane == 0) {
        int best = 0; float bv = acc[0];
#pragma unroll
        for (int e = 1; e < E_NUM; ++e) { if (acc[e] > bv) { bv = acc[e]; best = e; } }
        scale[t] = 1.f / (1.f + expf(-bv));
        int pos = atomicAdd(&counts[best << 5], 1);
        buckets[best * T_TOK + pos] = t;
    }
}

// ---------------- prep: router + w1t cvt (LDS transpose) --------------------
__global__ __launch_bounds__(256) void prep_kernel(
    const float* __restrict__ x, const float* __restrict__ gw,
    const float* __restrict__ gup,
    float* __restrict__ scale, int* __restrict__ counts,
    int* __restrict__ buckets, short* __restrict__ w1t)
{
    __shared__ float s[64 * 65];
    const int b = blockIdx.x;
    if (b < 1024) { router_body(b, x, gw, scale, counts, buckets); return; }

    const int idx = b - 1024;            // T1: gup [e][2048][2048], 8192 blocks
    tlds_body(gup, w1t, H_DIM, idx >> 10, (idx & 31) * 64, ((idx >> 5) & 31) * 64, s);
}

// ---------------- gather (inline padded prefix; solo) -----------------------
__global__ __launch_bounds__(256) void gather_kernel(
    const float* __restrict__ x, const float* __restrict__ scale,
    const int* __restrict__ counts, const int* __restrict__ buckets,
    short* __restrict__ xsg, int* __restrict__ slot_tok)
{
    const int r = blockIdx.x;            // slot row 0..5119
    int run = 0, eSel = 0, pos = 0;
    bool valid = false;
#pragma unroll
    for (int k = 0; k < E_NUM; ++k) {
        const int c  = counts[k << 5];
        const int cp = (c + 127) & ~127;
        if (r >= run && r < run + cp) { eSel = k; pos = r - run; valid = (pos < c); }
        run += cp;
    }
    const int tok = valid ? buckets[eSel * T_TOK + pos] : -1;
    if (threadIdx.x == 0) slot_tok[r] = tok;

    short* orow = xsg + (size_t)r * H_DIM + threadIdx.x * 8;
    if (!valid) {
        i32x4 z = {0, 0, 0, 0};
        *(i32x4*)orow = z;
        return;
    }
    const float sc = scale[tok];
    const float* xr = x + (size_t)tok * H_DIM + threadIdx.x * 8;
    float4 a = *(const float4*)xr;
    float4 c4 = *(const float4*)(xr + 4);
    short o[8] __attribute__((aligned(16)));
    o[0] = f2bf(a.x * sc);  o[1] = f2bf(a.y * sc);
    o[2] = f2bf(a.z * sc);  o[3] = f2bf(a.w * sc);
    o[4] = f2bf(c4.x * sc); o[5] = f2bf(c4.y * sc);
    o[6] = f2bf(c4.z * sc); o[7] = f2bf(c4.w * sc);
    *(i32x4*)orow = *(const i32x4*)o;
}

// ================== grouped MFMA GEMMs: 3-slot pipeline, 2x2 wave split =====
// (r22-proven best) counted vmcnt, raw s_barrier, bank swizzle.

#define GEMM_PIPE(NKT)                                                         \
    STG(0, 0); STG(1, 32); STG(2, 64);                                         \
    int cb = 0;                                                                \
    for (int t = 0; t < (NKT); ++t) {                                          \
        const int rem = (NKT) - 1 - t;                                         \
        if (rem >= 2)      asm volatile("s_waitcnt vmcnt(8)" ::: "memory");    \
        else if (rem == 1) asm volatile("s_waitcnt vmcnt(4)" ::: "memory");    \
        else               asm volatile("s_waitcnt vmcnt(0)" ::: "memory");    \
        __builtin_amdgcn_s_barrier();                                          \
        CMP(cb);                                                               \
        asm volatile("s_waitcnt lgkmcnt(0)" ::: "memory");                     \
        __builtin_amdgcn_sched_barrier(0);                                     \
        __builtin_amdgcn_s_barrier();                                          \
        if (t + 3 < (NKT)) STG(cb, (t + 3) * 32);                              \
        cb = (cb == 2) ? 0 : cb + 1;                                           \
    }

// ---------------- GEMM1 + SwiGLU, fused w2t cvt (LDS transpose) -------------
// blocks [0,640): gemm; [640,4736): dw -> w2t
__global__ __launch_bounds__(256) void gemm1_mfma_kernel(
    const short* __restrict__ xsg, const short* __restrict__ w1t,
    const int* __restrict__ counts, short* __restrict__ act,
    const float* __restrict__ dw, short* __restrict__ w2t)
{
    __shared__ short sA[3][4096];
    __shared__ short sB[3][4096];

    const int bid = blockIdx.x;
    if (bid >= 640) {
        const int idx = bid - 640;       // T2: dw [e][1024][2048], 4096 blocks
        float* s = (float*)&sA[0][0];
        tlds_body(dw, w2t, I_DIM, idx >> 9, (idx & 15) * 64, ((idx >> 4) & 31) * 64, s);
        return;
    }

    const int wg  = (bid & 7) * 80 + (bid >> 3);   // bijective: 640 % 8 == 0
    const int nt  = wg / MT;
    const int mt  = wg - nt * MT;
    const int m0  = mt << 7;
    const int f0  = nt << 6;

    int run = 0, e = 0;
#pragma unroll
    for (int k = 0; k < E_NUM; ++k) {
        if (m0 >= run) e = k;
        run += (counts[k << 5] + 127) & ~127;
    }
    if (m0 >= run) return;

    const int tid = threadIdx.x, lane = tid & 63, w = tid >> 6;
    const int wr = w >> 1, wc = w & 1;               // 2x2 wave grid
    const int lr = lane >> 2;
    const int cg = ((lane & 3) - (lane >> 3)) & 3;   // swizzled source chunk
    const int rA0 = (2 * w) * 16 + lr, rA1 = rA0 + 16;

    const short* srcA0 = xsg + (size_t)(m0 + rA0) * H_DIM + cg * 8;
    const short* srcA1 = xsg + (size_t)(m0 + rA1) * H_DIM + cg * 8;
    const int n0r = (rA0 < 64) ? (f0 + rA0) : (I_DIM + f0 + (rA0 & 63));
    const int n1r = (rA1 < 64) ? (f0 + rA1) : (I_DIM + f0 + (rA1 & 63));
    const short* srcB0 = w1t + ((size_t)e * TWO_I + n0r) * H_DIM + cg * 8;
    const short* srcB1 = w1t + ((size_t)e * TWO_I + n1r) * H_DIM + cg * 8;

    const int lm = lane & 15, lg = lane >> 4;
    const int ch = ((lg + (lm >> 1)) & 3) * 8;       // swizzled read chunk

    f32x4 acc[4][4];
#pragma unroll
    for (int i = 0; i < 4; ++i)
#pragma unroll
        for (int j = 0; j < 4; ++j) acc[i][j] = (f32x4){0.f, 0.f, 0.f, 0.f};

    auto STG = [&](int buf, int kb) {
        gload16(srcA0 + kb, &sA[buf][(2 * w) * 512]);
        gload16(srcA1 + kb, &sA[buf][(2 * w + 1) * 512]);
        gload16(srcB0 + kb, &sB[buf][(2 * w) * 512]);
        gload16(srcB1 + kb, &sB[buf][(2 * w + 1) * 512]);
    };
    auto CMP = [&](int buf) {
        bf16x8 av[4], bv[4];
#pragma unroll
        for (int mf = 0; mf < 4; ++mf)
            av[mf] = *(const bf16x8*)&sA[buf][(wr * 64 + mf * 16 + lm) * 32 + ch];
#pragma unroll
        for (int j = 0; j < 4; ++j) {
            const int bf = wc * 2 + ((j < 2) ? j : (j + 2));   // 2wc,2wc+1,2wc+4,2wc+5
            bv[j] = *(const bf16x8*)&sB[buf][(bf * 16 + lm) * 32 + ch];
        }
#pragma unroll
        for (int mf = 0; mf < 4; ++mf)
#pragma unroll
            for (int j = 0; j < 4; ++j)
                acc[mf][j] = __builtin_amdgcn_mfma_f32_16x16x32_bf16(av[mf], bv[j], acc[mf][j], 0, 0, 0);
    };

    GEMM_PIPE(H_DIM / 32)   // 64 K-iters

    // epilogue: act = up * gate * sigmoid(gate); up = acc[.][j], gate = acc[.][j+2]
    const int rbase = wr * 64 + lg * 4;
#pragma unroll
    for (int mf = 0; mf < 4; ++mf) {
#pragma unroll
        for (int rr = 0; rr < 4; ++rr) {
            const int row = rbase + mf * 16 + rr;
            short* orow = act + (size_t)(m0 + row) * I_DIM + f0 + lm;
#pragma unroll
            for (int j = 0; j < 2; ++j) {
                float up = acc[mf][j][rr];
                float gt = acc[mf][j + 2][rr];
                float v  = up * gt / (1.f + expf(-gt));
                orow[(2 * wc + j) * 16] = f2bf(v);
            }
        }
    }
}

// ---------------- GEMM2 (dense slots -> scatter out) ------------------------
__global__ __launch_bounds__(256) void gemm2_mfma_kernel(
    const short* __restrict__ actm, const short* __restrict__ w2t,
    const int* __restrict__ counts, const int* __restrict__ slot_tok,
    float* __restrict__ out)
{
    __shared__ short sA[3][4096];
    __shared__ short sB[3][4096];
    __shared__ int   sTok[128];

    const int bid = blockIdx.x;
    const int wg  = (bid & 7) * 80 + (bid >> 3);
    const int nt  = wg / MT;
    const int mt  = wg - nt * MT;
    const int m0  = mt << 7;
    const int h0  = nt << 7;

    int run = 0, e = 0;
#pragma unroll
    for (int k = 0; k < E_NUM; ++k) {
        if (m0 >= run) e = k;
        run += (counts[k << 5] + 127) & ~127;
    }
    if (m0 >= run) return;

    const int tid = threadIdx.x, lane = tid & 63, w = tid >> 6;
    if (tid < 128) sTok[tid] = slot_tok[m0 + tid];

    const int wr = w >> 1, wc = w & 1;
    const int lr = lane >> 2;
    const int cg = ((lane & 3) - (lane >> 3)) & 3;
    const int rA0 = (2 * w) * 16 + lr, rA1 = rA0 + 16;

    const short* srcA0 = actm + (size_t)(m0 + rA0) * I_DIM + cg * 8;
    const short* srcA1 = actm + (size_t)(m0 + rA1) * I_DIM + cg * 8;
    const short* srcB0 = w2t + ((size_t)e * H_DIM + h0 + rA0) * I_DIM + cg * 8;
    const short* srcB1 = w2t + ((size_t)e * H_DIM + h0 + rA1) * I_DIM + cg * 8;

    const int lm = lane & 15, lg = lane >> 4;
    const int ch = ((lg + (lm >> 1)) & 3) * 8;

    f32x4 acc[4][4];
#pragma unroll
    for (int i = 0; i < 4; ++i)
#pragma unroll
        for (int j = 0; j < 4; ++j) acc[i][j] = (f32x4){0.f, 0.f, 0.f, 0.f};

    auto STG = [&](int buf, int kb) {
        gload16(srcA0 + kb, &sA[buf][(2 * w) * 512]);
        gload16(srcA1 + kb, &sA[buf][(2 * w + 1) * 512]);
        gload16(srcB0 + kb, &sB[buf][(2 * w) * 512]);
        gload16(srcB1 + kb, &sB[buf][(2 * w + 1) * 512]);
    };
    auto CMP = [&](int buf) {
        bf16x8 av[4], bv[4];
#pragma unroll
        for (int mf = 0; mf < 4; ++mf)
            av[mf] = *(const bf16x8*)&sA[buf][(wr * 64 + mf * 16 + lm) * 32 + ch];
#pragma unroll
        for (int j = 0; j < 4; ++j)
            bv[j] = *(const bf16x8*)&sB[buf][((wc * 4 + j) * 16 + lm) * 32 + ch];
#pragma unroll
        for (int mf = 0; mf < 4; ++mf)
#pragma unroll
            for (int j = 0; j < 4; ++j)
                acc[mf][j] = __builtin_amdgcn_mfma_f32_16x16x32_bf16(av[mf], bv[j], acc[mf][j], 0, 0, 0);
    };

    GEMM_PIPE(I_DIM / 32)   // 32 K-iters

    const int rbase = wr * 64 + lg * 4;
#pragma unroll
    for (int mf = 0; mf < 4; ++mf) {
#pragma unroll
        for (int rr = 0; rr < 4; ++rr) {
            const int row = rbase + mf * 16 + rr;
            const int tok = sTok[row];
            if (tok < 0) continue;
            float* orow = out + (size_t)tok * H_DIM + h0 + lm;
#pragma unroll
            for (int j = 0; j < 4; ++j) orow[(wc * 4 + j) * 16] = acc[mf][j][rr];
        }
    }
}

extern "C" void kernel_launch(void* const* d_in, const int* in_sizes, int n_in,
                              void* d_out, int out_size, void* d_ws, size_t ws_size,
                              hipStream_t stream) {
    const float* x   = (const float*)d_in[0];
    const float* gw  = (const float*)d_in[1];
    const float* gup = (const float*)d_in[2];
    const float* dw  = (const float*)d_in[3];
    float* out = (float*)d_out;

    char* ws = (char*)d_ws;
    float* scale    = (float*)(ws + WS_SCALE);
    int*   counts   = (int*)(ws + WS_COUNTS);
    int*   buckets  = (int*)(ws + WS_BUCKETS);
    int*   slot_tok = (int*)(ws + WS_SLOTTOK);
    short* xsg      = (short*)(ws + WS_XSG);
    short* act      = (short*)(ws + WS_ACT);
    short* w1t      = (short*)(ws + WS_W1T);
    short* w2t      = (short*)(ws + WS_W2T);

    hipMemsetAsync(counts, 0, 256 * sizeof(int), stream);

    // router + w1t cvt (LDS transpose, coalesced writes)
    prep_kernel<<<1024 + 8192, 256, 0, stream>>>(
        x, gw, gup, scale, counts, buckets, w1t);

    // gather (solo, inline prefix)
    gather_kernel<<<MROWS, 256, 0, stream>>>(
        x, scale, counts, buckets, xsg, slot_tok);

    // gemm1 (640 blocks, 3-slot pipeline, 2x2 wave split) + w2t cvt (4096)
    gemm1_mfma_kernel<<<640 + 4096, 256, 0, stream>>>(xsg, w1t, counts, act, dw, w2t);

    gemm2_mfma_kernel<<<MT * 16, 256, 0, stream>>>(act, w2t, counts, slot_tok, out);
}